// Round 1
// baseline (8427.914 us; speedup 1.0000x reference)
//
#include <hip/hip_runtime.h>

constexpr int Nn  = 100000;  // nodes
constexpr int Rr  = 4;       // relations
constexpr int Ee  = 200000;  // edges per relation
constexpr int Din = 128;     // input feat dim
constexpr int Dh  = 256;     // hidden/output dim

typedef float  f32x4  __attribute__((ext_vector_type(4)));
typedef __bf16 bf16x4 __attribute__((ext_vector_type(4)));
typedef __bf16 bf16x8 __attribute__((ext_vector_type(8)));

// ---------------------------------------------------------------- degrees
__global__ __launch_bounds__(256) void count_deg_kernel(
    const int* __restrict__ src, const int* __restrict__ dst,
    int* __restrict__ dego, int* __restrict__ degi) {
  int i = blockIdx.x * 256 + threadIdx.x;
  if (i < Rr * Ee) {
    int r = i / Ee;
    atomicAdd(&dego[r * Nn + src[i]], 1);
    atomicAdd(&degi[r * Nn + dst[i]], 1);
  }
}

__global__ __launch_bounds__(256) void norms_kernel(
    const int* __restrict__ dego, const int* __restrict__ degi,
    float* __restrict__ ns, float* __restrict__ nd) {
  int i = blockIdx.x * 256 + threadIdx.x;
  if (i < Rr * Nn) {
    int a = dego[i]; if (a < 1) a = 1;
    int b = degi[i]; if (b < 1) b = 1;
    ns[i] = rsqrtf((float)a);
    nd[i] = rsqrtf((float)b);
  }
}

// ------------------------------------------------- out init = (1/R)*sum_r b_r
__global__ __launch_bounds__(256) void init_out_kernel(
    float* __restrict__ o, const float* __restrict__ b) {
  size_t i = (size_t)blockIdx.x * 256 + threadIdx.x;
  if (i < (size_t)Nn * Dh) {
    int c = (int)(i & (size_t)(Dh - 1));
    o[i] = 0.25f * (b[c] + b[Dh + c] + b[2 * Dh + c] + b[3 * Dh + c]);
  }
}

// ---------------------------------------------------------------- GEMM
// C[M,256] (+)= alpha * (diag(rowscale) * A[M,K]) @ B[K,256]  (+ bias[col])
// A,B f32 in memory, cast to bf16 for MFMA. 128x128 tile, 4 waves, BK=32.
template <int K, bool OUT_BF16, bool ACCUM>
__global__ __launch_bounds__(256) void gemm_bf16(
    const float* __restrict__ A, const float* __restrict__ B,
    void* __restrict__ Cv, const float* __restrict__ bias,
    const float* __restrict__ rowscale, float alpha, int M) {
  __shared__ __bf16 As[128][40];  // [m][k], +8 pad breaks frag-read conflicts
  __shared__ __bf16 Bs[128][40];  // [n][k] (transposed), +8 pad
  const int tid  = threadIdx.x;
  const int m0   = blockIdx.x * 128;
  const int nb   = blockIdx.y;  // 0/1 -> 128-col half
  const int w    = tid >> 6;
  const int lane = tid & 63;
  const int wr = w >> 1, wc = w & 1;
  const int l15 = lane & 15, quad = lane >> 4;
  f32x4 acc[4][4] = {};

  for (int kt = 0; kt < K / 32; ++kt) {
    // stage A tile [128][32]: 1024 float4 slots over 256 threads
#pragma unroll
    for (int it = 0; it < 4; ++it) {
      int i = tid + it * 256;
      int row = i >> 3;
      int col = (i & 7) << 2;
      int grow = m0 + row;
      f32x4 v = {0.f, 0.f, 0.f, 0.f};
      if (grow < M) {
        v = *(const f32x4*)(A + (size_t)grow * K + kt * 32 + col);
        if (rowscale) v *= rowscale[grow];
      }
      bf16x4 bv;
      bv[0] = (__bf16)v[0]; bv[1] = (__bf16)v[1];
      bv[2] = (__bf16)v[2]; bv[3] = (__bf16)v[3];
      *(bf16x4*)&As[row][col] = bv;
    }
    // stage B tile [32][128] -> transposed Bs[n][k]
#pragma unroll
    for (int it = 0; it < 4; ++it) {
      int i = tid + it * 256;
      int k = i >> 5;
      int n = (i & 31) << 2;
      f32x4 v = *(const f32x4*)(B + (size_t)(kt * 32 + k) * Dh + nb * 128 + n);
      Bs[n + 0][k] = (__bf16)v[0];
      Bs[n + 1][k] = (__bf16)v[1];
      Bs[n + 2][k] = (__bf16)v[2];
      Bs[n + 3][k] = (__bf16)v[3];
    }
    __syncthreads();
    bf16x8 af[4], bfr[4];
#pragma unroll
    for (int mt = 0; mt < 4; ++mt)
      af[mt] = *(const bf16x8*)&As[wr * 64 + mt * 16 + l15][quad * 8];
#pragma unroll
    for (int nt = 0; nt < 4; ++nt)
      bfr[nt] = *(const bf16x8*)&Bs[wc * 64 + nt * 16 + l15][quad * 8];
#pragma unroll
    for (int mt = 0; mt < 4; ++mt)
#pragma unroll
      for (int nt = 0; nt < 4; ++nt)
        acc[mt][nt] = __builtin_amdgcn_mfma_f32_16x16x32_bf16(
            af[mt], bfr[nt], acc[mt][nt], 0, 0, 0);
    __syncthreads();
  }

  // epilogue: C/D layout col=lane&15, row=quad*4+reg
#pragma unroll
  for (int mt = 0; mt < 4; ++mt) {
    int rl = wr * 64 + mt * 16 + quad * 4;
#pragma unroll
    for (int nt = 0; nt < 4; ++nt) {
      int col = nb * 128 + wc * 64 + nt * 16 + l15;
#pragma unroll
      for (int ri = 0; ri < 4; ++ri) {
        int grow = m0 + rl + ri;
        if (grow < M) {
          size_t idx = (size_t)grow * Dh + col;
          float v = alpha * acc[mt][nt][ri];
          if (bias) v += bias[col];
          if constexpr (OUT_BF16) {
            ((__bf16*)Cv)[idx] = (__bf16)v;
          } else {
            float* C = (float*)Cv;
            if constexpr (ACCUM) v += C[idx];
            C[idx] = v;
          }
        }
      }
    }
  }
}

// ------------------------------------------------------------- edge scatter
// one wave per edge: agg[dst] += x[src]*ns[src]*ew[e]   (256 cols, f32 atomics)
__global__ __launch_bounds__(256) void edge_scatter_kernel(
    const float* __restrict__ x, const __bf16* __restrict__ ew,
    const int* __restrict__ src, const int* __restrict__ dst,
    const float* __restrict__ ns, float* __restrict__ agg, int cnt) {
  int e = blockIdx.x * 4 + (threadIdx.x >> 6);
  if (e >= cnt) return;
  int lane = threadIdx.x & 63;
  int s = src[e], d = dst[e];
  float sc = ns[s];
  f32x4 xv = *(const f32x4*)(x + (size_t)s * Dh + lane * 4);
  bf16x4 ev = *(const bf16x4*)(ew + (size_t)e * Dh + lane * 4);
  float* ap = agg + (size_t)d * Dh + lane * 4;
  atomicAdd(ap + 0, xv[0] * sc * (float)ev[0]);
  atomicAdd(ap + 1, xv[1] * sc * (float)ev[1]);
  atomicAdd(ap + 2, xv[2] * sc * (float)ev[2]);
  atomicAdd(ap + 3, xv[3] * sc * (float)ev[3]);
}

// ---------------------------------------------------------------- launch
extern "C" void kernel_launch(void* const* d_in, const int* in_sizes, int n_in,
                              void* d_out, int out_size, void* d_ws, size_t ws_size,
                              hipStream_t stream) {
  const float* node_feat  = (const float*)d_in[0];
  const float* edge_w_raw = (const float*)d_in[1];
  const int*   src        = (const int*)d_in[2];
  const int*   dst        = (const int*)d_in[3];
  const float* Wn = (const float*)d_in[4];
  const float* bn = (const float*)d_in[5];
  const float* Wr = (const float*)d_in[6];
  const float* br = (const float*)d_in[7];
  const float* W1 = (const float*)d_in[8];
  const float* b1 = (const float*)d_in[9];
  const float* W2 = (const float*)d_in[10];
  const float* b2 = (const float*)d_in[11];
  float* out = (float*)d_out;

  char* ws = (char*)d_ws;
  size_t off = 0;
  auto alloc = [&](size_t bytes) -> void* {
    void* p = ws + off;
    off += (bytes + 255) & ~(size_t)255;
    return p;
  };
  float* ns  = (float*)alloc(sizeof(float) * (size_t)Rr * Nn);
  float* nd  = (float*)alloc(sizeof(float) * (size_t)Rr * Nn);
  float* x0  = (float*)alloc(sizeof(float) * (size_t)Nn * Dh);
  float* h1  = (float*)alloc(sizeof(float) * (size_t)Nn * Dh);
  float* agg = (float*)alloc(sizeof(float) * (size_t)Nn * Dh);
  size_t fixed = off;
  size_t ew_full_bytes = (size_t)Rr * Ee * Dh * 2;
  bool full = (fixed + ew_full_bytes) <= ws_size;
  __bf16* ew;
  int CH = Ee;
  if (full) {
    ew = (__bf16*)alloc(ew_full_bytes);
  } else {
    size_t avail = ws_size > fixed ? ws_size - fixed : 0;
    size_t ch = avail / ((size_t)Dh * 2);
    ch = (ch / 512) * 512;
    if (ch > (size_t)Ee) ch = (size_t)Ee;
    if (ch < 512) ch = 512;  // below this ws is unusable anyway
    CH = (int)ch;
    ew = (__bf16*)alloc((size_t)CH * Dh * 2);
  }

  // degrees live temporarily in the agg buffer (3.2 MB << 102.4 MB)
  int* dego = (int*)agg;
  int* degi = dego + (size_t)Rr * Nn;
  hipMemsetAsync(dego, 0, sizeof(int) * 2 * (size_t)Rr * Nn, stream);
  count_deg_kernel<<<(Rr * Ee + 255) / 256, 256, 0, stream>>>(src, dst, dego, degi);
  norms_kernel<<<(Rr * Nn + 255) / 256, 256, 0, stream>>>(dego, degi, ns, nd);

  // x0 = node_feat @ Wn + bn
  gemm_bf16<Din, false, false><<<dim3((Nn + 127) / 128, 2), 256, 0, stream>>>(
      node_feat, Wn, x0, bn, nullptr, 1.0f, Nn);

  if (full) {
    for (int r = 0; r < Rr; ++r)
      gemm_bf16<Din, true, false><<<dim3((Ee + 127) / 128, 2), 256, 0, stream>>>(
          edge_w_raw + (size_t)r * Ee * Din, Wr, ew + (size_t)r * Ee * Dh,
          br, nullptr, 1.0f, Ee);
  }

  for (int layer = 0; layer < 2; ++layer) {
    const float* x  = layer ? h1 : x0;
    float*       o  = layer ? out : h1;
    const float* W  = layer ? W2 : W1;
    const float* bb = layer ? b2 : b1;
    init_out_kernel<<<(int)(((size_t)Nn * Dh + 255) / 256), 256, 0, stream>>>(o, bb);
    for (int r = 0; r < Rr; ++r) {
      hipMemsetAsync(agg, 0, sizeof(float) * (size_t)Nn * Dh, stream);
      if (full) {
        edge_scatter_kernel<<<(Ee + 3) / 4, 256, 0, stream>>>(
            x, ew + (size_t)r * Ee * Dh, src + (size_t)r * Ee,
            dst + (size_t)r * Ee, ns + (size_t)r * Nn, agg, Ee);
      } else {
        for (int c0 = 0; c0 < Ee; c0 += CH) {
          int cnt = (Ee - c0 < CH) ? (Ee - c0) : CH;
          gemm_bf16<Din, true, false><<<dim3((cnt + 127) / 128, 2), 256, 0, stream>>>(
              edge_w_raw + ((size_t)r * Ee + c0) * Din, Wr, ew, br, nullptr, 1.0f, cnt);
          edge_scatter_kernel<<<(cnt + 3) / 4, 256, 0, stream>>>(
              x, ew, src + (size_t)r * Ee + c0, dst + (size_t)r * Ee + c0,
              ns + (size_t)r * Nn, agg, cnt);
        }
      }
      // o += 0.25 * (diag(nd_r) agg) @ W_r
      gemm_bf16<Dh, false, true><<<dim3((Nn + 127) / 128, 2), 256, 0, stream>>>(
          agg, W + (size_t)r * Dh * Dh, o, nullptr, nd + (size_t)r * Nn, 0.25f, Nn);
    }
  }
}

// Round 2
// 3680.984 us; speedup vs baseline: 2.2896x; 2.2896x over previous
//
#include <hip/hip_runtime.h>

constexpr int Nn  = 100000;  // nodes
constexpr int Rr  = 4;       // relations
constexpr int Ee  = 200000;  // edges per relation
constexpr int Din = 128;     // input feat dim
constexpr int Dh  = 256;     // hidden/output dim
constexpr int RN  = Rr * Nn; // 400000
constexpr int RE  = Rr * Ee; // 800000

typedef float  f32x4  __attribute__((ext_vector_type(4)));
typedef __bf16 bf16x4 __attribute__((ext_vector_type(4)));
typedef __bf16 bf16x8 __attribute__((ext_vector_type(8)));

// ---------------------------------------------------------------- degrees
__global__ __launch_bounds__(256) void count_deg_kernel(
    const int* __restrict__ src, const int* __restrict__ dst,
    int* __restrict__ dego, int* __restrict__ degi) {
  int i = blockIdx.x * 256 + threadIdx.x;
  if (i < RE) {
    int r = i / Ee;
    atomicAdd(&dego[r * Nn + src[i]], 1);
    atomicAdd(&degi[r * Nn + dst[i]], 1);
  }
}

__global__ __launch_bounds__(256) void norms_kernel(
    const int* __restrict__ dego, const int* __restrict__ degi,
    float* __restrict__ ns, float* __restrict__ nd) {
  int i = blockIdx.x * 256 + threadIdx.x;
  if (i < RN) {
    int a = dego[i]; if (a < 1) a = 1;
    int b = degi[i]; if (b < 1) b = 1;
    ns[i] = rsqrtf((float)a);
    nd[i] = rsqrtf((float)b);
  }
}

// ---------------------------------------------------------------- scan
// exclusive block scan of 256 per-thread sums; returns thread-exclusive
// prefix; wsum[4] holds the 4 wave totals afterwards (valid post-sync).
__device__ inline int block_excl_scan_256(int tsum, int tid, int* wsum) {
  int lane = tid & 63, w = tid >> 6;
  int inc = tsum;
#pragma unroll
  for (int off = 1; off < 64; off <<= 1) {
    int t = __shfl_up(inc, off);
    if (lane >= off) inc += t;
  }
  if (lane == 63) wsum[w] = inc;
  __syncthreads();
  int woff = 0;
  for (int i = 0; i < w; ++i) woff += wsum[i];
  return woff + inc - tsum;
}

// pass 1: per-1024-chunk exclusive scan, chunk totals to partials
__global__ __launch_bounds__(256) void scan1_kernel(
    const int* __restrict__ in, int* __restrict__ out,
    int* __restrict__ partials, int n) {
  __shared__ int wsum[4];
  int tid = threadIdx.x;
  int base = blockIdx.x * 1024 + tid * 4;
  int v[4];
#pragma unroll
  for (int j = 0; j < 4; ++j) v[j] = (base + j < n) ? in[base + j] : 0;
  int tsum = v[0] + v[1] + v[2] + v[3];
  int off = block_excl_scan_256(tsum, tid, wsum);
  int run = off;
#pragma unroll
  for (int j = 0; j < 4; ++j) {
    if (base + j < n) out[base + j] = run;
    run += v[j];
  }
  __syncthreads();
  if (tid == 0) partials[blockIdx.x] = wsum[0] + wsum[1] + wsum[2] + wsum[3];
}

// pass 2: exclusive scan of partials in-place (n <= 512), one block
__global__ __launch_bounds__(256) void scan2_kernel(int* __restrict__ p, int n) {
  __shared__ int wsum[4];
  int tid = threadIdx.x;
  int e0 = (2 * tid     < n) ? p[2 * tid]     : 0;
  int e1 = (2 * tid + 1 < n) ? p[2 * tid + 1] : 0;
  int off = block_excl_scan_256(e0 + e1, tid, wsum);
  if (2 * tid     < n) p[2 * tid]     = off;
  if (2 * tid + 1 < n) p[2 * tid + 1] = off + e0;
}

// pass 3: add chunk offsets; also write rowptr[n] = total edge count
__global__ __launch_bounds__(256) void scan3_kernel(
    int* __restrict__ out, const int* __restrict__ partials, int n) {
  int i = blockIdx.x * 256 + threadIdx.x;
  if (i < n) out[i] += partials[i >> 10];
  if (i == 0) out[n] = RE;
}

// fill CSR edge ids (order within a dst bucket is irrelevant: sum)
__global__ __launch_bounds__(256) void fill_eid_kernel(
    const int* __restrict__ dst, int* __restrict__ cursor,
    int* __restrict__ eid) {
  int i = blockIdx.x * 256 + threadIdx.x;
  if (i < RE) {
    int r = i / Ee;
    int pos = atomicAdd(&cursor[r * Nn + dst[i]], 1);
    eid[pos] = i;
  }
}

// ------------------------------------------------- out init = (1/R)*sum_r b_r
__global__ __launch_bounds__(256) void init_out_kernel(
    float* __restrict__ o, const float* __restrict__ b) {
  size_t i = (size_t)blockIdx.x * 256 + threadIdx.x;
  if (i < (size_t)Nn * Dh) {
    int c = (int)(i & (size_t)(Dh - 1));
    o[i] = 0.25f * (b[c] + b[Dh + c] + b[2 * Dh + c] + b[3 * Dh + c]);
  }
}

// ---------------------------------------------------------------- GEMM
// C[M,256] (+)= alpha * (diag(rowscale) * A[M,K]) @ B[K,256]  (+ bias[col])
template <int K, bool OUT_BF16, bool ACCUM>
__global__ __launch_bounds__(256) void gemm_bf16(
    const float* __restrict__ A, const float* __restrict__ B,
    void* __restrict__ Cv, const float* __restrict__ bias,
    const float* __restrict__ rowscale, float alpha, int M) {
  __shared__ __bf16 As[128][40];
  __shared__ __bf16 Bs[128][40];
  const int tid  = threadIdx.x;
  const int m0   = blockIdx.x * 128;
  const int nb   = blockIdx.y;
  const int w    = tid >> 6;
  const int lane = tid & 63;
  const int wr = w >> 1, wc = w & 1;
  const int l15 = lane & 15, quad = lane >> 4;
  f32x4 acc[4][4] = {};

  for (int kt = 0; kt < K / 32; ++kt) {
#pragma unroll
    for (int it = 0; it < 4; ++it) {
      int i = tid + it * 256;
      int row = i >> 3;
      int col = (i & 7) << 2;
      int grow = m0 + row;
      f32x4 v = {0.f, 0.f, 0.f, 0.f};
      if (grow < M) {
        v = *(const f32x4*)(A + (size_t)grow * K + kt * 32 + col);
        if (rowscale) v *= rowscale[grow];
      }
      bf16x4 bv;
      bv[0] = (__bf16)v[0]; bv[1] = (__bf16)v[1];
      bv[2] = (__bf16)v[2]; bv[3] = (__bf16)v[3];
      *(bf16x4*)&As[row][col] = bv;
    }
#pragma unroll
    for (int it = 0; it < 4; ++it) {
      int i = tid + it * 256;
      int k = i >> 5;
      int n = (i & 31) << 2;
      f32x4 v = *(const f32x4*)(B + (size_t)(kt * 32 + k) * Dh + nb * 128 + n);
      Bs[n + 0][k] = (__bf16)v[0];
      Bs[n + 1][k] = (__bf16)v[1];
      Bs[n + 2][k] = (__bf16)v[2];
      Bs[n + 3][k] = (__bf16)v[3];
    }
    __syncthreads();
    bf16x8 af[4], bfr[4];
#pragma unroll
    for (int mt = 0; mt < 4; ++mt)
      af[mt] = *(const bf16x8*)&As[wr * 64 + mt * 16 + l15][quad * 8];
#pragma unroll
    for (int nt = 0; nt < 4; ++nt)
      bfr[nt] = *(const bf16x8*)&Bs[wc * 64 + nt * 16 + l15][quad * 8];
#pragma unroll
    for (int mt = 0; mt < 4; ++mt)
#pragma unroll
      for (int nt = 0; nt < 4; ++nt)
        acc[mt][nt] = __builtin_amdgcn_mfma_f32_16x16x32_bf16(
            af[mt], bfr[nt], acc[mt][nt], 0, 0, 0);
    __syncthreads();
  }

#pragma unroll
  for (int mt = 0; mt < 4; ++mt) {
    int rl = wr * 64 + mt * 16 + quad * 4;
#pragma unroll
    for (int nt = 0; nt < 4; ++nt) {
      int col = nb * 128 + wc * 64 + nt * 16 + l15;
#pragma unroll
      for (int ri = 0; ri < 4; ++ri) {
        int grow = m0 + rl + ri;
        if (grow < M) {
          size_t idx = (size_t)grow * Dh + col;
          float v = alpha * acc[mt][nt][ri];
          if (bias) v += bias[col];
          if constexpr (OUT_BF16) {
            ((__bf16*)Cv)[idx] = (__bf16)v;
          } else {
            float* C = (float*)Cv;
            if constexpr (ACCUM) v += C[idx];
            C[idx] = v;
          }
        }
      }
    }
  }
}

// ------------------------------------------------------------- CSR aggregate
// one wave per dst node: agg[n] = sum_{e in CSR[n]} x[src[e]]*ns[src[e]]*ew[e]
__global__ __launch_bounds__(256) void aggregate_kernel(
    const float* __restrict__ x, const __bf16* __restrict__ ew,
    const int* __restrict__ src, const int* __restrict__ rowptr_r,
    const int* __restrict__ eid, const float* __restrict__ ns_r,
    float* __restrict__ agg) {
  int n = blockIdx.x * 4 + (threadIdx.x >> 6);
  if (n >= Nn) return;
  int lane = threadIdx.x & 63;
  int p0 = rowptr_r[n], p1 = rowptr_r[n + 1];
  f32x4 acc = {0.f, 0.f, 0.f, 0.f};
  for (int p = p0; p < p1; ++p) {
    int ge = eid[p];
    int s = src[ge];
    float sc = ns_r[s];
    f32x4  xv = *(const f32x4*)(x + (size_t)s * Dh + lane * 4);
    bf16x4 ev = *(const bf16x4*)(ew + (size_t)ge * Dh + lane * 4);
    acc[0] += xv[0] * sc * (float)ev[0];
    acc[1] += xv[1] * sc * (float)ev[1];
    acc[2] += xv[2] * sc * (float)ev[2];
    acc[3] += xv[3] * sc * (float)ev[3];
  }
  *(f32x4*)(agg + (size_t)n * Dh + lane * 4) = acc;
}

// ------------------------------------- fallback atomic scatter (chunked ws)
__global__ __launch_bounds__(256) void edge_scatter_kernel(
    const float* __restrict__ x, const __bf16* __restrict__ ew,
    const int* __restrict__ src, const int* __restrict__ dst,
    const float* __restrict__ ns, float* __restrict__ agg, int cnt) {
  int e = blockIdx.x * 4 + (threadIdx.x >> 6);
  if (e >= cnt) return;
  int lane = threadIdx.x & 63;
  int s = src[e], d = dst[e];
  float sc = ns[s];
  f32x4 xv = *(const f32x4*)(x + (size_t)s * Dh + lane * 4);
  bf16x4 ev = *(const bf16x4*)(ew + (size_t)e * Dh + lane * 4);
  float* ap = agg + (size_t)d * Dh + lane * 4;
  atomicAdd(ap + 0, xv[0] * sc * (float)ev[0]);
  atomicAdd(ap + 1, xv[1] * sc * (float)ev[1]);
  atomicAdd(ap + 2, xv[2] * sc * (float)ev[2]);
  atomicAdd(ap + 3, xv[3] * sc * (float)ev[3]);
}

// ---------------------------------------------------------------- launch
extern "C" void kernel_launch(void* const* d_in, const int* in_sizes, int n_in,
                              void* d_out, int out_size, void* d_ws, size_t ws_size,
                              hipStream_t stream) {
  const float* node_feat  = (const float*)d_in[0];
  const float* edge_w_raw = (const float*)d_in[1];
  const int*   src        = (const int*)d_in[2];
  const int*   dst        = (const int*)d_in[3];
  const float* Wn = (const float*)d_in[4];
  const float* bn = (const float*)d_in[5];
  const float* Wr = (const float*)d_in[6];
  const float* br = (const float*)d_in[7];
  const float* W1 = (const float*)d_in[8];
  const float* b1 = (const float*)d_in[9];
  const float* W2 = (const float*)d_in[10];
  const float* b2 = (const float*)d_in[11];
  float* out = (float*)d_out;

  char* ws = (char*)d_ws;
  size_t off = 0;
  auto alloc = [&](size_t bytes) -> void* {
    void* p = ws + off;
    off += (bytes + 255) & ~(size_t)255;
    return p;
  };
  float* ns     = (float*)alloc(sizeof(float) * RN);
  float* nd     = (float*)alloc(sizeof(float) * RN);
  int*   rowptr = (int*)alloc(sizeof(int) * (RN + 1));
  int*   cursor = (int*)alloc(sizeof(int) * RN);
  int*   eid    = (int*)alloc(sizeof(int) * RE);
  int*   parts  = (int*)alloc(sizeof(int) * 512);
  float* x0  = (float*)alloc(sizeof(float) * (size_t)Nn * Dh);
  float* h1  = (float*)alloc(sizeof(float) * (size_t)Nn * Dh);
  float* agg = (float*)alloc(sizeof(float) * (size_t)Nn * Dh);
  size_t fixed = off;
  size_t ew_full_bytes = (size_t)RE * Dh * 2;
  bool full = (fixed + ew_full_bytes) <= ws_size;
  __bf16* ew;
  int CH = Ee;
  if (full) {
    ew = (__bf16*)alloc(ew_full_bytes);
  } else {
    size_t avail = ws_size > fixed ? ws_size - fixed : 0;
    size_t ch = avail / ((size_t)Dh * 2);
    ch = (ch / 512) * 512;
    if (ch > (size_t)Ee) ch = (size_t)Ee;
    if (ch < 512) ch = 512;
    CH = (int)ch;
    ew = (__bf16*)alloc((size_t)CH * Dh * 2);
  }

  // degrees live temporarily in the agg buffer (3.2 MB << 102.4 MB)
  int* dego = (int*)agg;
  int* degi = dego + RN;
  hipMemsetAsync(dego, 0, sizeof(int) * 2 * (size_t)RN, stream);
  count_deg_kernel<<<(RE + 255) / 256, 256, 0, stream>>>(src, dst, dego, degi);
  norms_kernel<<<(RN + 255) / 256, 256, 0, stream>>>(dego, degi, ns, nd);

  // CSR build (shared by both layers): scan degi -> rowptr, fill eid
  int nchunks = (RN + 1023) / 1024;  // 391
  scan1_kernel<<<nchunks, 256, 0, stream>>>(degi, rowptr, parts, RN);
  scan2_kernel<<<1, 256, 0, stream>>>(parts, nchunks);
  scan3_kernel<<<(RN + 255) / 256, 256, 0, stream>>>(rowptr, parts, RN);
  hipMemcpyAsync(cursor, rowptr, sizeof(int) * RN, hipMemcpyDeviceToDevice, stream);
  fill_eid_kernel<<<(RE + 255) / 256, 256, 0, stream>>>(dst, cursor, eid);

  // x0 = node_feat @ Wn + bn
  gemm_bf16<Din, false, false><<<dim3((Nn + 127) / 128, 2), 256, 0, stream>>>(
      node_feat, Wn, x0, bn, nullptr, 1.0f, Nn);

  if (full) {
    for (int r = 0; r < Rr; ++r)
      gemm_bf16<Din, true, false><<<dim3((Ee + 127) / 128, 2), 256, 0, stream>>>(
          edge_w_raw + (size_t)r * Ee * Din, Wr, ew + (size_t)r * Ee * Dh,
          br, nullptr, 1.0f, Ee);
  }

  for (int layer = 0; layer < 2; ++layer) {
    const float* x  = layer ? h1 : x0;
    float*       o  = layer ? out : h1;
    const float* W  = layer ? W2 : W1;
    const float* bb = layer ? b2 : b1;
    init_out_kernel<<<(int)(((size_t)Nn * Dh + 255) / 256), 256, 0, stream>>>(o, bb);
    for (int r = 0; r < Rr; ++r) {
      if (full) {
        aggregate_kernel<<<(Nn + 3) / 4, 256, 0, stream>>>(
            x, ew, src, rowptr + (size_t)r * Nn, eid, ns + (size_t)r * Nn, agg);
      } else {
        hipMemsetAsync(agg, 0, sizeof(float) * (size_t)Nn * Dh, stream);
        for (int c0 = 0; c0 < Ee; c0 += CH) {
          int cnt = (Ee - c0 < CH) ? (Ee - c0) : CH;
          gemm_bf16<Din, true, false><<<dim3((cnt + 127) / 128, 2), 256, 0, stream>>>(
              edge_w_raw + ((size_t)r * Ee + c0) * Din, Wr, ew, br, nullptr, 1.0f, cnt);
          edge_scatter_kernel<<<(cnt + 3) / 4, 256, 0, stream>>>(
              x, ew, src + (size_t)r * Ee + c0, dst + (size_t)r * Ee + c0,
              ns + (size_t)r * Nn, agg, cnt);
        }
      }
      // o += 0.25 * (diag(nd_r) agg) @ W_r
      gemm_bf16<Dh, false, true><<<dim3((Nn + 127) / 128, 2), 256, 0, stream>>>(
          agg, W + (size_t)r * Dh * Dh, o, nullptr, nd + (size_t)r * Nn, 0.25f, Nn);
    }
  }
}